// Round 5
// baseline (312.056 us; speedup 1.0000x reference)
//
#include <hip/hip_runtime.h>
#include <math.h>

#define Bsz 2
#define Ssz 2048
#define Esz 1024
#define Hn  16
#define Dd  64
#define PADC 72   // LDS row pitch in shorts (144 B, 16B-aligned, frag reads 2-way)

typedef unsigned short ushort_t;
typedef short bf16x8 __attribute__((ext_vector_type(8)));
typedef float f32x4 __attribute__((ext_vector_type(4)));

#define GLD16(g, l) __builtin_amdgcn_global_load_lds(                        \
    (const __attribute__((address_space(1))) unsigned int*)(g),              \
    (__attribute__((address_space(3))) unsigned int*)(l), 16, 0, 0)

#define KF 0.045084220027780106f   // (1/sqrt(E)) * log2(e), folded into Q

// ---------------------------------------------------------------------------
// RoPE cos/sin table: tc/ts[s*32 + p], fp64-accurate.
// ---------------------------------------------------------------------------
__global__ __launch_bounds__(256) void rope_table_kernel(float* tc, float* ts)
{
    const int idx = blockIdx.x * 256 + threadIdx.x;   // 65536 total
    const int s = idx >> 5, p = idx & 31;
    const double c = 9.210340371976184257 / 32.0;     // ln(10000)/32
    const double inv = exp(-c * (double)p);
    double sn, cs;
    sincos((double)s * inv, &sn, &cs);
    tc[idx] = (float)cs;
    ts[idx] = (float)sn;
}

// ---------------------------------------------------------------------------
// bf16 helpers
// ---------------------------------------------------------------------------
__device__ inline ushort_t bf16_rn(float x)
{
    unsigned u = __float_as_uint(x);
    return (ushort_t)((u + 0x7FFFu + ((u >> 16) & 1u)) >> 16);
}

// ---------------------------------------------------------------------------
// fp32 -> bf16 (round-nearest), 7 tensors via blockIdx.z.
// z 0..2: size n_big (q,k,v);  z 3..6: size n_small (W_q,W_k,W_v,W_o).
// ---------------------------------------------------------------------------
__global__ __launch_bounds__(256) void cvt_kernel(
    const float* s0, const float* s1, const float* s2, const float* s3,
    const float* s4, const float* s5, const float* s6,
    ushort_t* d0, ushort_t* d1, ushort_t* d2, ushort_t* d3,
    ushort_t* d4, ushort_t* d5, ushort_t* d6, int n_big, int n_small)
{
    const float* s; ushort_t* d;
    switch (blockIdx.z) {
        case 0: s = s0; d = d0; break;
        case 1: s = s1; d = d1; break;
        case 2: s = s2; d = d2; break;
        case 3: s = s3; d = d3; break;
        case 4: s = s4; d = d4; break;
        case 5: s = s5; d = d5; break;
        default: s = s6; d = d6; break;
    }
    const int n = (blockIdx.z < 3) ? n_big : n_small;
    const int i = (blockIdx.x * 256 + threadIdx.x) * 4;
    if (i >= n) return;
    float4 v = *(const float4*)(s + i);
    ushort4 o;
    o.x = bf16_rn(v.x); o.y = bf16_rn(v.y);
    o.z = bf16_rn(v.z); o.w = bf16_rn(v.w);
    *(ushort4*)(d + i) = o;
}

// ---------------------------------------------------------------------------
// Pure-bf16 projection GEMM, m97 structure: tile 128x128, BK=32, 4 waves
// (2x2), each wave 64x64 = 4x4 frags of 16x16x32.  16 MFMA + 8 ds_read_b128
// + 4 global_load_lds_dwordx4 per K-iter.
//   z=0: Q -> RoPE -> *KF -> bf16 [b,h,s,d]
//   z=1: K -> RoPE ->        bf16 [b,h,s,d]
//   z=2: V ->                bf16 [b,h,d,s]  (transposed for PV B-operand)
// ---------------------------------------------------------------------------
__global__ __launch_bounds__(256) void proj_gemm_kernel(
    const ushort_t* __restrict__ Aq, const ushort_t* __restrict__ Ak,
    const ushort_t* __restrict__ Av,
    const ushort_t* __restrict__ Wq, const ushort_t* __restrict__ Wk,
    const ushort_t* __restrict__ Wv,
    ushort_t* __restrict__ Yq, ushort_t* __restrict__ Yk,
    ushort_t* __restrict__ Yv,
    const float* __restrict__ tc, const float* __restrict__ ts)
{
    const int z = blockIdx.z;
    const ushort_t* Ag = (z == 0) ? Aq : (z == 1) ? Ak : Av;
    const ushort_t* Wg = (z == 0) ? Wq : (z == 1) ? Wk : Wv;
    ushort_t*       Yg = (z == 0) ? Yq : (z == 1) ? Yk : Yv;

    __shared__ __align__(16) ushort_t sA[128 * 32];
    __shared__ __align__(16) ushort_t sB[128 * 32];

    const int t    = threadIdx.x;
    const int lane = t & 63;
    const int w    = t >> 6;
    const int wm   = (w & 1) * 64;
    const int wn   = (w >> 1) * 64;
    const int fr   = lane & 15;
    const int g    = lane >> 4;
    const int kq   = g * 8;
    const int n0   = blockIdx.x * 128;
    const int m0   = blockIdx.y * 128;

    const ushort_t* pA = Ag + (size_t)(m0 + (t >> 2)) * 1024 + (t & 3) * 8;
    const ushort_t* pB = Wg + (size_t)(n0 + (t >> 2)) * 1024 + (t & 3) * 8;

    f32x4 acc[4][4];
#pragma unroll
    for (int mi = 0; mi < 4; ++mi)
#pragma unroll
        for (int ni = 0; ni < 4; ++ni) acc[mi][ni] = (f32x4)0.f;

    for (int k0 = 0; k0 < 1024; k0 += 32) {
        GLD16(pA + k0,             &sA[t * 8]);
        GLD16(pA + k0 + 64 * 1024, &sA[2048 + t * 8]);
        GLD16(pB + k0,             &sB[t * 8]);
        GLD16(pB + k0 + 64 * 1024, &sB[2048 + t * 8]);
        __syncthreads();

        bf16x8 a[4], b[4];
#pragma unroll
        for (int mi = 0; mi < 4; ++mi)
            a[mi] = *(const bf16x8*)&sA[(wm + mi * 16 + fr) * 32 + kq];
#pragma unroll
        for (int ni = 0; ni < 4; ++ni)
            b[ni] = *(const bf16x8*)&sB[(wn + ni * 16 + fr) * 32 + kq];
#pragma unroll
        for (int mi = 0; mi < 4; ++mi)
#pragma unroll
            for (int ni = 0; ni < 4; ++ni)
                acc[mi][ni] = __builtin_amdgcn_mfma_f32_16x16x32_bf16(
                    a[mi], b[ni], acc[mi][ni], 0, 0, 0);
        __syncthreads();
    }

    // epilogue.  C/D: col = lane&15, row = (lane>>4)*4 + reg.
#pragma unroll
    for (int mi = 0; mi < 4; ++mi)
#pragma unroll
        for (int ni = 0; ni < 4; ++ni) {
            const int col   = n0 + wn + ni * 16 + fr;
            const int rbase = m0 + wm + mi * 16 + g * 4;
            const int hh = col >> 6, d = col & 63, pi = d >> 1;
#pragma unroll
            for (int rg = 0; rg < 4; ++rg) {
                const int srow = rbase + rg;
                const int b_ = srow >> 11, s = srow & (Ssz - 1);
                float v  = acc[mi][ni][rg];
                float pt = __shfl_xor(v, 1, 64);   // RoPE partner (col^1)
                float o  = v;
                if (z < 2) {
                    const float cs = tc[s * 32 + pi];
                    const float sn = ts[s * 32 + pi];
                    o = (d & 1) ? fmaf(v, cs, pt * sn)
                                : fmaf(v, cs, -pt * sn);
                    if (z == 0) o *= KF;           // fold softmax scale into Q
                }
                const size_t idx = (z == 2)
                    ? (((size_t)(b_ * Hn + hh)) * Dd + d) * Ssz + s
                    : (((size_t)(b_ * Hn + hh)) * Ssz + s) * Dd + d;
                Yg[idx] = bf16_rn(o);
            }
        }
}

// ---------------------------------------------------------------------------
// Pure-bf16 MFMA flash attention, no-max softmax, 128-row q-tile.
// Qb,Kb: bf16 [b,h,s,d] (Q pre-scaled by KF).  Vtb: bf16 [b,h,d,s].
// 4 waves x 32 q-rows; KV tiles of 64.  P truncated to bf16, stored to sP
// with XOR-swizzled 8-short blocks (kills g-group bank conflicts).
// Output: bf16 [b,s,e].
// ---------------------------------------------------------------------------
__global__ __launch_bounds__(256) void attn_kernel(
    const ushort_t* __restrict__ Qb, const ushort_t* __restrict__ Kb,
    const ushort_t* __restrict__ Vtb, ushort_t* __restrict__ Ob)
{
    __shared__ __align__(16) ushort_t sK[64 * PADC];
    __shared__ __align__(16) ushort_t sV[64 * PADC];
    __shared__ __align__(16) ushort_t sP[128 * PADC];

    const int t    = threadIdx.x;
    const int lane = t & 63;
    const int w    = t >> 6;
    const int fr   = lane & 15;
    const int g    = lane >> 4;
    const int kq   = g * 8;
    const int bh   = blockIdx.y;
    const int q0   = blockIdx.x * 128;

    const int frh = fr >> 3;            // 0/1
    const int frl = fr & 7;
    const int fq  = (fr >> 2) & 3;      // (row>>2)&3 for pa reads

    // sP swizzled store-col per nt, and read k-offset per ks (lane consts)
    int scolP[4], krdP[2];
#pragma unroll
    for (int nt = 0; nt < 4; ++nt)
        scolP[nt] = (((nt * 2 + frh) ^ g) << 3) + frl;
#pragma unroll
    for (int ks = 0; ks < 2; ++ks)
        krdP[ks] = ((4 * ks + g) ^ fq) << 3;

    // Q A-fragments: rows w*32 + mt*16 + fr (reused for all KV steps)
    bf16x8 qa[2][2];
#pragma unroll
    for (int mt = 0; mt < 2; ++mt) {
        const size_t qbase = ((size_t)bh * Ssz + q0 + w * 32 + mt * 16 + fr) * Dd;
        qa[mt][0] = *(const bf16x8*)(Qb + qbase + kq);
        qa[mt][1] = *(const bf16x8*)(Qb + qbase + 32 + kq);
    }

    float lp[2][4];
    f32x4 Oacc[2][4];
#pragma unroll
    for (int mt = 0; mt < 2; ++mt) {
#pragma unroll
        for (int rg = 0; rg < 4; ++rg) lp[mt][rg] = 0.f;
#pragma unroll
        for (int dt = 0; dt < 4; ++dt) Oacc[mt][dt] = (f32x4)0.f;
    }

    const int srow = t >> 3;            // 0..31
    const int scol = (t & 7) * 8;
    const size_t kgb = (size_t)bh * Ssz * Dd;
    const size_t vgb = (size_t)bh * Dd * Ssz;

    for (int kv0 = 0; kv0 < Ssz; kv0 += 64) {
#pragma unroll
        for (int rr = 0; rr < 2; ++rr) {
            const int row = srow + rr * 32;
            *(uint4*)&sK[row * PADC + scol] =
                *(const uint4*)(Kb + kgb + (size_t)(kv0 + row) * Dd + scol);
            *(uint4*)&sV[row * PADC + scol] =
                *(const uint4*)(Vtb + vgb + (size_t)row * Ssz + kv0 + scol);
        }
        __syncthreads();

        // QK^T: 2 mt x 4 nt x 2 ks = 16 MFMA
        f32x4 S[2][4];
#pragma unroll
        for (int mt = 0; mt < 2; ++mt)
#pragma unroll
            for (int nt = 0; nt < 4; ++nt) S[mt][nt] = (f32x4)0.f;
#pragma unroll
        for (int ks = 0; ks < 2; ++ks)
#pragma unroll
            for (int nt = 0; nt < 4; ++nt) {
                bf16x8 kfrag = *(const bf16x8*)&sK[(nt * 16 + fr) * PADC + ks * 32 + kq];
#pragma unroll
                for (int mt = 0; mt < 2; ++mt)
                    S[mt][nt] = __builtin_amdgcn_mfma_f32_16x16x32_bf16(
                        qa[mt][ks], kfrag, S[mt][nt], 0, 0, 0);
            }

        // p = exp2(S); truncate to bf16 (bias cancels in softmax ratio)
#pragma unroll
        for (int mt = 0; mt < 2; ++mt)
#pragma unroll
            for (int nt = 0; nt < 4; ++nt)
#pragma unroll
                for (int rg = 0; rg < 4; ++rg) {
                    const float p = exp2f(S[mt][nt][rg]);
                    lp[mt][rg] += p;
                    sP[(w * 32 + mt * 16 + g * 4 + rg) * PADC + scolP[nt]] =
                        (ushort_t)(__float_as_uint(p) >> 16);
                }
        __syncthreads();

        // PV: 2 ks x 4 dt x 2 mt = 16 MFMA
#pragma unroll
        for (int ks = 0; ks < 2; ++ks) {
            bf16x8 pa[2];
#pragma unroll
            for (int mt = 0; mt < 2; ++mt)
                pa[mt] = *(const bf16x8*)&sP[(w * 32 + mt * 16 + fr) * PADC + krdP[ks]];
#pragma unroll
            for (int dt = 0; dt < 4; ++dt) {
                bf16x8 vfrag = *(const bf16x8*)&sV[(dt * 16 + fr) * PADC + ks * 32 + kq];
#pragma unroll
                for (int mt = 0; mt < 2; ++mt)
                    Oacc[mt][dt] = __builtin_amdgcn_mfma_f32_16x16x32_bf16(
                        pa[mt], vfrag, Oacc[mt][dt], 0, 0, 0);
            }
        }
        __syncthreads();
    }

    // reduce row sums across the 16 fr lanes (xor<16 stays within g-group)
#pragma unroll
    for (int mt = 0; mt < 2; ++mt)
#pragma unroll
        for (int rg = 0; rg < 4; ++rg) {
#pragma unroll
            for (int mk = 1; mk <= 8; mk <<= 1)
                lp[mt][rg] += __shfl_xor(lp[mt][rg], mk, 64);
        }

    // epilogue: O -> bf16 [b,s,e]
    const int b = bh >> 4, h = bh & 15;
#pragma unroll
    for (int mt = 0; mt < 2; ++mt)
#pragma unroll
        for (int rg = 0; rg < 4; ++rg) {
            const int s = q0 + w * 32 + mt * 16 + g * 4 + rg;
            const float inv = 1.f / lp[mt][rg];
#pragma unroll
            for (int dt = 0; dt < 4; ++dt) {
                const float o = Oacc[mt][dt][rg] * inv;
                Ob[((size_t)(b * Ssz + s)) * Esz + h * Dd + dt * 16 + fr] = bf16_rn(o);
            }
        }
}

// ---------------------------------------------------------------------------
// Pure-bf16 final GEMM (m97 structure): out = O @ W_o^T, fp32 out.
// ---------------------------------------------------------------------------
__global__ __launch_bounds__(256) void final_gemm_kernel(
    const ushort_t* __restrict__ Ag, const ushort_t* __restrict__ Bg,
    float* __restrict__ Yf)
{
    __shared__ __align__(16) ushort_t sA[128 * 32];
    __shared__ __align__(16) ushort_t sB[128 * 32];

    const int t    = threadIdx.x;
    const int lane = t & 63;
    const int w    = t >> 6;
    const int wm   = (w & 1) * 64;
    const int wn   = (w >> 1) * 64;
    const int fr   = lane & 15;
    const int g    = lane >> 4;
    const int kq   = g * 8;
    const int n0   = blockIdx.x * 128;
    const int m0   = blockIdx.y * 128;

    const ushort_t* pA = Ag + (size_t)(m0 + (t >> 2)) * 1024 + (t & 3) * 8;
    const ushort_t* pB = Bg + (size_t)(n0 + (t >> 2)) * 1024 + (t & 3) * 8;

    f32x4 acc[4][4];
#pragma unroll
    for (int mi = 0; mi < 4; ++mi)
#pragma unroll
        for (int ni = 0; ni < 4; ++ni) acc[mi][ni] = (f32x4)0.f;

    for (int k0 = 0; k0 < 1024; k0 += 32) {
        GLD16(pA + k0,             &sA[t * 8]);
        GLD16(pA + k0 + 64 * 1024, &sA[2048 + t * 8]);
        GLD16(pB + k0,             &sB[t * 8]);
        GLD16(pB + k0 + 64 * 1024, &sB[2048 + t * 8]);
        __syncthreads();

        bf16x8 a[4], b[4];
#pragma unroll
        for (int mi = 0; mi < 4; ++mi)
            a[mi] = *(const bf16x8*)&sA[(wm + mi * 16 + fr) * 32 + kq];
#pragma unroll
        for (int ni = 0; ni < 4; ++ni)
            b[ni] = *(const bf16x8*)&sB[(wn + ni * 16 + fr) * 32 + kq];
#pragma unroll
        for (int mi = 0; mi < 4; ++mi)
#pragma unroll
            for (int ni = 0; ni < 4; ++ni)
                acc[mi][ni] = __builtin_amdgcn_mfma_f32_16x16x32_bf16(
                    a[mi], b[ni], acc[mi][ni], 0, 0, 0);
        __syncthreads();
    }

#pragma unroll
    for (int mi = 0; mi < 4; ++mi)
#pragma unroll
        for (int ni = 0; ni < 4; ++ni) {
            const int col   = n0 + wn + ni * 16 + fr;
            const int rbase = m0 + wm + mi * 16 + g * 4;
#pragma unroll
            for (int rg = 0; rg < 4; ++rg)
                Yf[(size_t)(rbase + rg) * 1024 + col] = acc[mi][ni][rg];
        }
}

// ---------------------------------------------------------------------------
extern "C" void kernel_launch(void* const* d_in, const int* in_sizes, int n_in,
                              void* d_out, int out_size, void* d_ws, size_t ws_size,
                              hipStream_t stream)
{
    (void)in_sizes; (void)n_in; (void)out_size; (void)ws_size;
    const float* q   = (const float*)d_in[0];
    const float* k   = (const float*)d_in[1];
    const float* v   = (const float*)d_in[2];
    const float* W_q = (const float*)d_in[3];
    const float* W_k = (const float*)d_in[4];
    const float* W_v = (const float*)d_in[5];
    const float* W_o = (const float*)d_in[6];
    float* out = (float*)d_out;

    const size_t NQ = (size_t)Bsz * Ssz * Esz;   // 4,194,304
    const size_t NW = (size_t)Esz * Esz;         // 1,048,576

    float* ws = (float*)d_ws;
    float* tc = ws;                  // 65536
    float* ts = ws + 65536;          // 65536

    ushort_t* us  = (ushort_t*)(ws + 131072);
    ushort_t* qb  = us;              // bf16 inputs
    ushort_t* kb  = qb + NQ;
    ushort_t* vb  = kb + NQ;
    ushort_t* wqb = vb + NQ;         // bf16 weights
    ushort_t* wkb = wqb + NW;
    ushort_t* wvb = wkb + NW;
    ushort_t* wob = wvb + NW;
    ushort_t* pq  = wob + NW;        // projected bf16 tensors
    ushort_t* pk  = pq + NQ;
    ushort_t* pv  = pk + NQ;
    ushort_t* ob  = pv + NQ;         // attention output bf16

    dim3 blk(256);

    rope_table_kernel<<<dim3(256), blk, 0, stream>>>(tc, ts);

    cvt_kernel<<<dim3(4096, 1, 7), blk, 0, stream>>>(
        q, k, v, W_q, W_k, W_v, W_o,
        qb, kb, vb, wqb, wkb, wvb, wob, (int)NQ, (int)NW);

    proj_gemm_kernel<<<dim3(Esz / 128, (Bsz * Ssz) / 128, 3), blk, 0, stream>>>(
        qb, kb, vb, wqb, wkb, wvb, pq, pk, pv, tc, ts);

    attn_kernel<<<dim3(Ssz / 128, Bsz * Hn), blk, 0, stream>>>(pq, pk, pv, ob);

    final_gemm_kernel<<<dim3(Esz / 128, (Bsz * Ssz) / 128), blk, 0, stream>>>(
        ob, wob, out);
}

// Round 7
// 295.865 us; speedup vs baseline: 1.0547x; 1.0547x over previous
//
#include <hip/hip_runtime.h>
#include <math.h>

#define Bsz 2
#define Ssz 2048
#define Esz 1024
#define Hn  16
#define Dd  64
#define PADC 72    // attn LDS pitch in shorts (144 B)
#define TP   136   // proj epilogue LDS tile pitch in shorts (272 B, 16B-aligned rows)
#define FP   68    // final epilogue LDS tile pitch in floats (272 B)

typedef unsigned short ushort_t;
typedef short bf16x8 __attribute__((ext_vector_type(8)));
typedef short bf16x4 __attribute__((ext_vector_type(4)));
typedef float f32x4 __attribute__((ext_vector_type(4)));

#define GLD16(g, l) __builtin_amdgcn_global_load_lds(                        \
    (const __attribute__((address_space(1))) unsigned int*)(g),              \
    (__attribute__((address_space(3))) unsigned int*)(l), 16, 0, 0)

#define KF 0.045084220027780106f   // (1/sqrt(E)) * log2(e), folded into Q

#define MFMA32(a, b, c) __builtin_amdgcn_mfma_f32_16x16x32_bf16((a), (b), (c), 0, 0, 0)
// gfx950 supports v_mfma_f32_16x16x16_bf16 (ISA §10); builtin spelling is the
// gfx90a-lineage "_1k" name.  NOTE: no __has_builtin guard — it returns 0 on
// the host pass and would #error (round-6 failure).
#define MFMA16(a, b, c) __builtin_amdgcn_mfma_f32_16x16x16bf16_1k((a), (b), (c), 0, 0, 0)

// ---------------------------------------------------------------------------
// bf16 helpers
// ---------------------------------------------------------------------------
__device__ inline ushort_t bf16_rn(float x)
{
    unsigned u = __float_as_uint(x);
    return (ushort_t)((u + 0x7FFFu + ((u >> 16) & 1u)) >> 16);
}

// ---------------------------------------------------------------------------
// fp32 -> bf16 convert (7 tensors) + RoPE table build (z=7).
// z 0..2: size n_big (q,k,v);  z 3..6: size n_small (W_q,W_k,W_v,W_o).
// z 7: tc/ts[s*32+p] fp64-accurate cos/sin.
// ---------------------------------------------------------------------------
__global__ __launch_bounds__(256) void cvt_kernel(
    const float* s0, const float* s1, const float* s2, const float* s3,
    const float* s4, const float* s5, const float* s6,
    ushort_t* d0, ushort_t* d1, ushort_t* d2, ushort_t* d3,
    ushort_t* d4, ushort_t* d5, ushort_t* d6,
    float* tc, float* ts, int n_big, int n_small)
{
    if (blockIdx.z == 7) {
        const int idx = blockIdx.x * 256 + threadIdx.x;
        if (idx < Ssz * 32) {
            const int s = idx >> 5, p = idx & 31;
            const double c = 9.210340371976184257 / 32.0;   // ln(10000)/32
            const double inv = exp(-c * (double)p);
            double sn, cs;
            sincos((double)s * inv, &sn, &cs);
            tc[idx] = (float)cs;
            ts[idx] = (float)sn;
        }
        return;
    }
    const float* s; ushort_t* d;
    switch (blockIdx.z) {
        case 0: s = s0; d = d0; break;
        case 1: s = s1; d = d1; break;
        case 2: s = s2; d = d2; break;
        case 3: s = s3; d = d3; break;
        case 4: s = s4; d = d4; break;
        case 5: s = s5; d = d5; break;
        default: s = s6; d = d6; break;
    }
    const int n = (blockIdx.z < 3) ? n_big : n_small;
    const int i = (blockIdx.x * 256 + threadIdx.x) * 4;
    if (i >= n) return;
    float4 v = *(const float4*)(s + i);
    ushort4 o;
    o.x = bf16_rn(v.x); o.y = bf16_rn(v.y);
    o.z = bf16_rn(v.z); o.w = bf16_rn(v.w);
    *(ushort4*)(d + i) = o;
}

// ---------------------------------------------------------------------------
// Pure-bf16 projection GEMM (m97 structure, tile 128x128, BK=32, 4 waves).
//   z=0: Q -> RoPE -> *KF -> bf16 [b,h,s,d]
//   z=1: K -> RoPE ->        bf16 [b,h,s,d]
//   z=2: V ->                bf16 [b,h,d,s]  (transposed for PV B-operand)
// Epilogue: stage tile in LDS (bf16, pitch TP), read back linearly and issue
// dense 16-B stores; z=2 reads the tile transposed so stores run along s.
// ---------------------------------------------------------------------------
__global__ __launch_bounds__(256) void proj_gemm_kernel(
    const ushort_t* __restrict__ Aq, const ushort_t* __restrict__ Ak,
    const ushort_t* __restrict__ Av,
    const ushort_t* __restrict__ Wq, const ushort_t* __restrict__ Wk,
    const ushort_t* __restrict__ Wv,
    ushort_t* __restrict__ Yq, ushort_t* __restrict__ Yk,
    ushort_t* __restrict__ Yv,
    const float* __restrict__ tc, const float* __restrict__ ts)
{
    const int z = blockIdx.z;
    const ushort_t* Ag = (z == 0) ? Aq : (z == 1) ? Ak : Av;
    const ushort_t* Wg = (z == 0) ? Wq : (z == 1) ? Wk : Wv;
    ushort_t*       Yg = (z == 0) ? Yq : (z == 1) ? Yk : Yv;

    __shared__ __align__(16) ushort_t sA[128 * 32];
    __shared__ __align__(16) ushort_t sB[128 * 32];
    __shared__ __align__(16) ushort_t Tb[128 * TP];

    const int t    = threadIdx.x;
    const int lane = t & 63;
    const int w    = t >> 6;
    const int wm   = (w & 1) * 64;
    const int wn   = (w >> 1) * 64;
    const int fr   = lane & 15;
    const int g    = lane >> 4;
    const int kq   = g * 8;
    const int n0   = blockIdx.x * 128;
    const int m0   = blockIdx.y * 128;

    const ushort_t* pA = Ag + (size_t)(m0 + (t >> 2)) * 1024 + (t & 3) * 8;
    const ushort_t* pB = Wg + (size_t)(n0 + (t >> 2)) * 1024 + (t & 3) * 8;

    f32x4 acc[4][4];
#pragma unroll
    for (int mi = 0; mi < 4; ++mi)
#pragma unroll
        for (int ni = 0; ni < 4; ++ni) acc[mi][ni] = (f32x4)0.f;

    for (int k0 = 0; k0 < 1024; k0 += 32) {
        GLD16(pA + k0,             &sA[t * 8]);
        GLD16(pA + k0 + 64 * 1024, &sA[2048 + t * 8]);
        GLD16(pB + k0,             &sB[t * 8]);
        GLD16(pB + k0 + 64 * 1024, &sB[2048 + t * 8]);
        __syncthreads();

        bf16x8 a[4], b[4];
#pragma unroll
        for (int mi = 0; mi < 4; ++mi)
            a[mi] = *(const bf16x8*)&sA[(wm + mi * 16 + fr) * 32 + kq];
#pragma unroll
        for (int ni = 0; ni < 4; ++ni)
            b[ni] = *(const bf16x8*)&sB[(wn + ni * 16 + fr) * 32 + kq];
#pragma unroll
        for (int mi = 0; mi < 4; ++mi)
#pragma unroll
            for (int ni = 0; ni < 4; ++ni)
                acc[mi][ni] = MFMA32(a[mi], b[ni], acc[mi][ni]);
        __syncthreads();
    }

    // ---- epilogue: RoPE in-register, stage bf16 tile to LDS ----
#pragma unroll
    for (int mi = 0; mi < 4; ++mi)
#pragma unroll
        for (int ni = 0; ni < 4; ++ni) {
            const int col = wn + ni * 16 + fr;          // 0..127 (tile col)
            const int d   = (n0 + col) & 63;
            const int pi  = d >> 1;
#pragma unroll
            for (int rg = 0; rg < 4; ++rg) {
                const int row = wm + mi * 16 + g * 4 + rg;   // 0..127
                const int s   = (m0 + row) & (Ssz - 1);
                float v  = acc[mi][ni][rg];
                float pt = __shfl_xor(v, 1, 64);   // RoPE partner (col^1)
                float o  = v;
                if (z < 2) {
                    const float cs = tc[s * 32 + pi];
                    const float sn = ts[s * 32 + pi];
                    o = (d & 1) ? fmaf(v, cs, pt * sn)
                                : fmaf(v, cs, -pt * sn);
                    if (z == 0) o *= KF;
                }
                Tb[row * TP + col] = bf16_rn(o);
            }
        }
    __syncthreads();

    if (z < 2) {
        // [b,h,s,d]: row -> (b,s); 16 chunks of 8 shorts per row
        const int row = t >> 1;
        const int m   = m0 + row;
        const int b   = m >> 11, s = m & (Ssz - 1);
#pragma unroll
        for (int i = 0; i < 8; ++i) {
            const int ic = (t & 1) * 8 + i;             // chunk 0..15
            uint4 val = *(const uint4*)&Tb[row * TP + ic * 8];
            const int hh = (n0 >> 6) + (ic >> 3);
            const int d  = (ic & 7) * 8;
            *(uint4*)&Yg[(((size_t)(b * Hn + hh)) * Ssz + s) * Dd + d] = val;
        }
    } else {
        // [b,h,d,s]: col -> (h,d); contiguous along s (= tile rows)
        const int col = t >> 1;
        const int hh  = (n0 >> 6) + (col >> 6);
        const int d   = col & 63;
        const int b   = m0 >> 11;
        const int sg  = (m0 & (Ssz - 1)) + (t & 1) * 64;
        const size_t base = (((size_t)(b * Hn + hh)) * Dd + d) * Ssz + sg;
#pragma unroll
        for (int jj = 0; jj < 8; ++jj) {
            uint4 val;
            unsigned vv[4];
#pragma unroll
            for (int qd = 0; qd < 4; ++qd) {
                const int r0 = (t & 1) * 64 + jj * 8 + qd * 2;
                const unsigned lo = Tb[(r0 + 0) * TP + col];
                const unsigned hi = Tb[(r0 + 1) * TP + col];
                vv[qd] = lo | (hi << 16);
            }
            val.x = vv[0]; val.y = vv[1]; val.z = vv[2]; val.w = vv[3];
            *(uint4*)&Yg[base + jj * 8] = val;
        }
    }
}

// ---------------------------------------------------------------------------
// Pure-bf16 MFMA flash attention, S^T formulation (P stays in registers).
// Qb,Kb: bf16 [b,h,s,d] (Q pre-scaled by KF).  Vtb: bf16 [b,h,d,s].
// 4 waves x 32 q-rows (128-row q-tile); KV tiles of 64; no-max softmax.
// S^T = mfma(K,Q) puts P[q=fr][c=g*4+reg] in the A-layout of the
// 16x16x16 bf16 mfma, so PV needs no LDS round-trip for P.
// ---------------------------------------------------------------------------
__global__ __launch_bounds__(256) void attn_kernel(
    const ushort_t* __restrict__ Qb, const ushort_t* __restrict__ Kb,
    const ushort_t* __restrict__ Vtb, ushort_t* __restrict__ Ob)
{
    __shared__ __align__(16) ushort_t sK[64 * PADC];
    __shared__ __align__(16) ushort_t sV[64 * PADC];

    const int t    = threadIdx.x;
    const int lane = t & 63;
    const int w    = t >> 6;
    const int fr   = lane & 15;
    const int g    = lane >> 4;
    const int kq   = g * 8;
    const int bh   = blockIdx.y;
    const int q0   = blockIdx.x * 128;

    // Q fragments (B-operand of S^T): rows w*32 + mt*16 + fr
    bf16x8 qa[2][2];
#pragma unroll
    for (int mt = 0; mt < 2; ++mt) {
        const size_t qbase = ((size_t)bh * Ssz + q0 + w * 32 + mt * 16 + fr) * Dd;
        qa[mt][0] = *(const bf16x8*)(Qb + qbase + kq);
        qa[mt][1] = *(const bf16x8*)(Qb + qbase + 32 + kq);
    }

    float lp[2] = {0.f, 0.f};      // per-lane row sums, q = fr
    f32x4 Oacc[2][4];
#pragma unroll
    for (int mt = 0; mt < 2; ++mt)
#pragma unroll
        for (int dt = 0; dt < 4; ++dt) Oacc[mt][dt] = (f32x4)0.f;

    const int srow = t >> 3;       // 0..31
    const int scol = (t & 7) * 8;
    const size_t kgb = (size_t)bh * Ssz * Dd;
    const size_t vgb = (size_t)bh * Dd * Ssz;

    for (int kv0 = 0; kv0 < Ssz; kv0 += 64) {
#pragma unroll
        for (int rr = 0; rr < 2; ++rr) {
            const int row = srow + rr * 32;
            *(uint4*)&sK[row * PADC + scol] =
                *(const uint4*)(Kb + kgb + (size_t)(kv0 + row) * Dd + scol);
            *(uint4*)&sV[row * PADC + scol] =
                *(const uint4*)(Vtb + vgb + (size_t)row * Ssz + kv0 + scol);
        }
        __syncthreads();

        // S^T: A=K (lane fr -> kv), B=Q (lane fr -> q).  16 MFMA.
        f32x4 St[2][4];
#pragma unroll
        for (int mt = 0; mt < 2; ++mt)
#pragma unroll
            for (int nt = 0; nt < 4; ++nt) St[mt][nt] = (f32x4)0.f;
#pragma unroll
        for (int ks = 0; ks < 2; ++ks)
#pragma unroll
            for (int nt = 0; nt < 4; ++nt) {
                bf16x8 kfrag = *(const bf16x8*)&sK[(nt * 16 + fr) * PADC + ks * 32 + kq];
#pragma unroll
                for (int mt = 0; mt < 2; ++mt)
                    St[mt][nt] = MFMA32(kfrag, qa[mt][ks], St[mt][nt]);
            }

        // exp2 + truncate-pack into 16x16x16 A-fragments (P[q=fr][c=g*4+j])
        bf16x4 pf[2][4];
#pragma unroll
        for (int mt = 0; mt < 2; ++mt)
#pragma unroll
            for (int nt = 0; nt < 4; ++nt) {
                const float p0 = exp2f(St[mt][nt][0]);
                const float p1 = exp2f(St[mt][nt][1]);
                const float p2 = exp2f(St[mt][nt][2]);
                const float p3 = exp2f(St[mt][nt][3]);
                lp[mt] += (p0 + p1) + (p2 + p3);
                union { unsigned u[2]; bf16x4 s; } pk;
                pk.u[0] = (__float_as_uint(p0) >> 16) | (__float_as_uint(p1) & 0xFFFF0000u);
                pk.u[1] = (__float_as_uint(p2) >> 16) | (__float_as_uint(p3) & 0xFFFF0000u);
                pf[mt][nt] = pk.s;
            }

        // PV: B = V^T fragment (b64), 32 MFMA of 16x16x16
#pragma unroll
        for (int nt = 0; nt < 4; ++nt)
#pragma unroll
            for (int dt = 0; dt < 4; ++dt) {
                bf16x4 vfrag = *(const bf16x4*)&sV[(dt * 16 + fr) * PADC + nt * 16 + g * 4];
#pragma unroll
                for (int mt = 0; mt < 2; ++mt)
                    Oacc[mt][dt] = MFMA16(pf[mt][nt], vfrag, Oacc[mt][dt]);
            }
        __syncthreads();
    }

    // reduce row sums across g-groups (lanes with same fr)
#pragma unroll
    for (int mt = 0; mt < 2; ++mt) {
        lp[mt] += __shfl_xor(lp[mt], 16, 64);
        lp[mt] += __shfl_xor(lp[mt], 32, 64);
    }

    // epilogue: O[q = g*4+rg][d = dt*16+fr] -> bf16 [b,s,e]
    const int b = bh >> 4, h = bh & 15;
#pragma unroll
    for (int mt = 0; mt < 2; ++mt)
#pragma unroll
        for (int rg = 0; rg < 4; ++rg) {
            const float lv  = __shfl(lp[mt], (lane & 48) + g * 4 + rg, 64);
            const float inv = 1.f / lv;
            const int s = q0 + w * 32 + mt * 16 + g * 4 + rg;
#pragma unroll
            for (int dt = 0; dt < 4; ++dt) {
                const float o = Oacc[mt][dt][rg] * inv;
                Ob[((size_t)(b * Ssz + s)) * Esz + h * Dd + dt * 16 + fr] = bf16_rn(o);
            }
        }
}

// ---------------------------------------------------------------------------
// Pure-bf16 final GEMM (m97 structure): out = O @ W_o^T, fp32 out.
// LDS-staged epilogue in two 64-col halves -> dense float4 stores.
// ---------------------------------------------------------------------------
__global__ __launch_bounds__(256) void final_gemm_kernel(
    const ushort_t* __restrict__ Ag, const ushort_t* __restrict__ Bg,
    float* __restrict__ Yf)
{
    __shared__ __align__(16) ushort_t sA[128 * 32];
    __shared__ __align__(16) ushort_t sB[128 * 32];
    __shared__ __align__(16) float Tf[128 * FP];

    const int t    = threadIdx.x;
    const int lane = t & 63;
    const int w    = t >> 6;
    const int wm   = (w & 1) * 64;
    const int wn   = (w >> 1) * 64;
    const int fr   = lane & 15;
    const int g    = lane >> 4;
    const int kq   = g * 8;
    const int n0   = blockIdx.x * 128;
    const int m0   = blockIdx.y * 128;

    const ushort_t* pA = Ag + (size_t)(m0 + (t >> 2)) * 1024 + (t & 3) * 8;
    const ushort_t* pB = Bg + (size_t)(n0 + (t >> 2)) * 1024 + (t & 3) * 8;

    f32x4 acc[4][4];
#pragma unroll
    for (int mi = 0; mi < 4; ++mi)
#pragma unroll
        for (int ni = 0; ni < 4; ++ni) acc[mi][ni] = (f32x4)0.f;

    for (int k0 = 0; k0 < 1024; k0 += 32) {
        GLD16(pA + k0,             &sA[t * 8]);
        GLD16(pA + k0 + 64 * 1024, &sA[2048 + t * 8]);
        GLD16(pB + k0,             &sB[t * 8]);
        GLD16(pB + k0 + 64 * 1024, &sB[2048 + t * 8]);
        __syncthreads();

        bf16x8 a[4], b[4];
#pragma unroll
        for (int mi = 0; mi < 4; ++mi)
            a[mi] = *(const bf16x8*)&sA[(wm + mi * 16 + fr) * 32 + kq];
#pragma unroll
        for (int ni = 0; ni < 4; ++ni)
            b[ni] = *(const bf16x8*)&sB[(wn + ni * 16 + fr) * 32 + kq];
#pragma unroll
        for (int mi = 0; mi < 4; ++mi)
#pragma unroll
            for (int ni = 0; ni < 4; ++ni)
                acc[mi][ni] = MFMA32(a[mi], b[ni], acc[mi][ni]);
        __syncthreads();
    }

    // epilogue: two 64-col halves through LDS -> dense float4 stores
#pragma unroll
    for (int hf = 0; hf < 2; ++hf) {
        if ((w >> 1) == hf) {
#pragma unroll
            for (int mi = 0; mi < 4; ++mi)
#pragma unroll
                for (int ni = 0; ni < 4; ++ni) {
                    const int col = ni * 16 + fr;                 // 0..63
#pragma unroll
                    for (int rg = 0; rg < 4; ++rg)
                        Tf[(wm + mi * 16 + g * 4 + rg) * FP + col] = acc[mi][ni][rg];
                }
        }
        __syncthreads();
        const int row = t >> 1;
        float* dst = Yf + (size_t)(m0 + row) * 1024 + n0 + hf * 64 + (t & 1) * 32;
        const float* src = &Tf[row * FP + (t & 1) * 32];
#pragma unroll
        for (int i = 0; i < 8; ++i)
            *(float4*)(dst + i * 4) = *(const float4*)(src + i * 4);
        __syncthreads();
    }
}

// ---------------------------------------------------------------------------
extern "C" void kernel_launch(void* const* d_in, const int* in_sizes, int n_in,
                              void* d_out, int out_size, void* d_ws, size_t ws_size,
                              hipStream_t stream)
{
    (void)in_sizes; (void)n_in; (void)out_size; (void)ws_size;
    const float* q   = (const float*)d_in[0];
    const float* k   = (const float*)d_in[1];
    const float* v   = (const float*)d_in[2];
    const float* W_q = (const float*)d_in[3];
    const float* W_k = (const float*)d_in[4];
    const float* W_v = (const float*)d_in[5];
    const float* W_o = (const float*)d_in[6];
    float* out = (float*)d_out;

    const size_t NQ = (size_t)Bsz * Ssz * Esz;   // 4,194,304
    const size_t NW = (size_t)Esz * Esz;         // 1,048,576

    float* ws = (float*)d_ws;
    float* tc = ws;                  // 65536
    float* ts = ws + 65536;          // 65536

    ushort_t* us  = (ushort_t*)(ws + 131072);
    ushort_t* qb  = us;              // bf16 inputs
    ushort_t* kb  = qb + NQ;
    ushort_t* vb  = kb + NQ;
    ushort_t* wqb = vb + NQ;         // bf16 weights
    ushort_t* wkb = wqb + NW;
    ushort_t* wvb = wkb + NW;
    ushort_t* wob = wvb + NW;
    ushort_t* pq  = wob + NW;        // projected bf16 tensors
    ushort_t* pk  = pq + NQ;
    ushort_t* pv  = pk + NQ;
    ushort_t* ob  = pv + NQ;         // attention output bf16

    dim3 blk(256);

    cvt_kernel<<<dim3(4096, 1, 8), blk, 0, stream>>>(
        q, k, v, W_q, W_k, W_v, W_o,
        qb, kb, vb, wqb, wkb, wvb, wob, tc, ts, (int)NQ, (int)NW);

    proj_gemm_kernel<<<dim3(Esz / 128, (Bsz * Ssz) / 128, 3), blk, 0, stream>>>(
        qb, kb, vb, wqb, wkb, wvb, pq, pk, pv, tc, ts);

    attn_kernel<<<dim3(Ssz / 128, Bsz * Hn), blk, 0, stream>>>(pq, pk, pv, ob);

    final_gemm_kernel<<<dim3(Esz / 128, (Bsz * Ssz) / 128), blk, 0, stream>>>(
        ob, wob, out);
}